// Round 1
// baseline (8211.958 us; speedup 1.0000x reference)
//
#include <hip/hip_runtime.h>

// SimpleLSTM: B=128, T=8192, H=96 (4H=384 gates), input dim 1, output dim 1.
// One block per batch element (recurrence over T is sequential; gates of one
// batch must stay in one block). Thread j in [0,384) owns gate j; its w_hh row
// (96 floats) lives in registers. h is broadcast through LDS each step.

#define T_LEN 8192
#define H_DIM 96
#define G_DIM 384  // 4*H

__device__ __forceinline__ float fast_sigmoid(float v) {
    return 1.0f / (1.0f + __expf(-v));
}
__device__ __forceinline__ float fast_tanh(float v) {
    // 1 - 2/(e^{2v}+1); stable: e^inf -> inf -> 1, e^-inf -> 0 -> -1
    return 1.0f - 2.0f / (__expf(2.0f * v) + 1.0f);
}

__global__ __launch_bounds__(G_DIM, 1) void lstm_seq_kernel(
    const float* __restrict__ x,      // [B, T, 1]
    const float* __restrict__ w_ih,   // [4H, 1]
    const float* __restrict__ w_hh,   // [4H, H]
    const float* __restrict__ b_ih,   // [4H]
    const float* __restrict__ b_hh,   // [4H]
    const float* __restrict__ w_out,  // [1, H]
    const float* __restrict__ b_out,  // [1]
    float* __restrict__ y)            // [B, T, 1]
{
    const int b = blockIdx.x;
    const int j = threadIdx.x;        // gate index 0..383
    const int lane = j & 63;

    __shared__ float h_s[H_DIM];
    __shared__ float act_s[G_DIM];
    __shared__ float red_s[2];

    // Per-thread w_hh row j (96 floats = 24 float4, rows are 384B -> 16B aligned)
    float4 wv[24];
    {
        const float4* wrow = reinterpret_cast<const float4*>(w_hh + j * H_DIM);
        #pragma unroll
        for (int q = 0; q < 24; ++q) wv[q] = wrow[q];
    }

    const float bias_j = b_ih[j] + b_hh[j];
    const float wih_j  = w_ih[j];
    const float wout_j = (j < H_DIM) ? w_out[j] : 0.0f;
    const float bout   = b_out[0];

    float c = 0.0f;
    if (j < H_DIM) h_s[j] = 0.0f;
    __syncthreads();

    const float* xrow = x + (size_t)b * T_LEN;
    float* yrow = y + (size_t)b * T_LEN;
    float x_next = xrow[0];

    for (int t = 0; t < T_LEN; ++t) {
        const float x_cur = x_next;
        if (t + 1 < T_LEN) x_next = xrow[t + 1];

        // gate preactivation: bias + x*w_ih + dot(h, w_hh[j, :])
        // 4 accumulator chains (24 deep) to break the serial FMA dependency.
        float a0 = bias_j + x_cur * wih_j, a1 = 0.0f, a2 = 0.0f, a3 = 0.0f;
        const float4* h4 = reinterpret_cast<const float4*>(h_s);
        #pragma unroll
        for (int q = 0; q < 24; ++q) {
            const float4 hv = h4[q];  // broadcast ds_read_b128, conflict-free
            a0 += hv.x * wv[q].x;
            a1 += hv.y * wv[q].y;
            a2 += hv.z * wv[q].z;
            a3 += hv.w * wv[q].w;
        }
        const float acc = (a0 + a1) + (a2 + a3);

        // nonlinearity: gates i,f,o -> sigmoid; gate g (rows 192..287) -> tanh
        float a;
        if (j >= 2 * H_DIM && j < 3 * H_DIM) a = fast_tanh(acc);
        else                                 a = fast_sigmoid(acc);
        act_s[j] = a;
        __syncthreads();  // act_s ready; everyone done reading h_s

        float partial = 0.0f;
        if (j < H_DIM) {
            const float ig = act_s[j];
            const float fg = act_s[H_DIM + j];
            const float gg = act_s[2 * H_DIM + j];
            const float og = act_s[3 * H_DIM + j];
            c = fg * c + ig * gg;
            const float h = og * fast_tanh(c);
            h_s[j] = h;
            partial = h * wout_j;
        }
        // y_t = sum_k h[k]*w_out[k]: waves 0 (j 0..63) and 1 (j 64..95, rest 0)
        if (j < 128) {
            #pragma unroll
            for (int off = 32; off > 0; off >>= 1)
                partial += __shfl_down(partial, off, 64);
            if (lane == 0) red_s[j >> 6] = partial;
        }
        __syncthreads();  // h_s ready for next step; red_s ready

        if (j == 0) yrow[t] = red_s[0] + red_s[1] + bout;
    }
}

extern "C" void kernel_launch(void* const* d_in, const int* in_sizes, int n_in,
                              void* d_out, int out_size, void* d_ws, size_t ws_size,
                              hipStream_t stream) {
    const float* x     = (const float*)d_in[0];
    const float* w_ih  = (const float*)d_in[1];
    const float* w_hh  = (const float*)d_in[2];
    const float* b_ih  = (const float*)d_in[3];
    const float* b_hh  = (const float*)d_in[4];
    const float* w_out = (const float*)d_in[5];
    const float* b_out = (const float*)d_in[6];
    float* y = (float*)d_out;

    const int B = 128;
    lstm_seq_kernel<<<dim3(B), dim3(G_DIM), 0, stream>>>(
        x, w_ih, w_hh, b_ih, b_hh, w_out, b_out, y);
}